// Round 10
// baseline (181.787 us; speedup 1.0000x reference)
//
#include <hip/hip_runtime.h>

typedef short short8 __attribute__((ext_vector_type(8)));
typedef float f32x4 __attribute__((ext_vector_type(4)));

#define NV 131072
#define KK 27
#define CH 64
#define NP 4      // ci phases; chunk = NV*CE*2B = 4.2 MB ~ one XCD L2
#define CE 16     // channels per chunk
#define NG2 14    // tap-pair groups per phase (2*14=28, tap 27 -> zero weights)

#define FENCE asm volatile("" ::: "memory")

__device__ inline unsigned short f2b(float f) {
    unsigned u = __float_as_uint(f);
    u += 0x7fffu + ((u >> 16) & 1u);   // round-to-nearest-even
    return (unsigned short)(u >> 16);
}

// feat f32 [N][64] -> chunk-major bf16 xc[4][N][16]
__global__ void prep_featc(const float* __restrict__ feat, unsigned short* __restrict__ xc) {
    int tid = blockIdx.x * blockDim.x + threadIdx.x;   // N*16 threads
    int j = tid >> 4, u = tid & 15;
    float4 v = *reinterpret_cast<const float4*>(feat + j * CH + u * 4);
    int p = u >> 2, e0 = (u & 3) * 4;
    ushort4 o;
    o.x = f2b(v.x); o.y = f2b(v.y); o.z = f2b(v.z); o.w = f2b(v.w);
    *reinterpret_cast<ushort4*>(xc + ((size_t)p * NV + j) * CE + e0) = o;
}

// W [27][64][64] f32 -> wq [NP][NG2][nt 4][lane 64][8e] bf16, exactly the per-lane
// ds_read order. lane=(kg,lr): col=nt*16+lr, kk=kg*8+e, tap=2g+(kk>>4), ci=p*16+(kk&15).
__global__ void prep_wq(const float* __restrict__ W1, const float* __restrict__ W2,
                        unsigned short* __restrict__ wq1, unsigned short* __restrict__ wq2) {
    const int PER = NP * NG2 * 4 * 64 * 8;             // 114688
    int id = blockIdx.x * blockDim.x + threadIdx.x;    // 2*PER
    const float* W = W1; unsigned short* wq = wq1;
    int r = id;
    if (r >= PER) { r -= PER; W = W2; wq = wq2; }
    int e = r & 7, lane = (r >> 3) & 63, nt = (r >> 9) & 3, q = r >> 11;
    int g = q % NG2, p = q / NG2;
    int col = nt * 16 + (lane & 15);
    int kk  = (lane >> 4) * 8 + e;
    int k   = 2 * g + (kk >> 4);
    int ci  = p * CE + (kk & 15);
    float v = (k < KK) ? W[(k * CH + ci) * CH + col] : 0.f;
    wq[r] = f2b(v);
}

__device__ inline void gld16(const void* gsrc, void* ldst) {
    __builtin_amdgcn_global_load_lds(
        (const __attribute__((address_space(1))) unsigned int*)gsrc,
        (__attribute__((address_space(3))) unsigned int*)ldst,
        16, 0, 0);
}

// Block = 512 thr = 8 waves, wave owns 64 rows x 64 cols; grid = N/512 = 256 -> 1 block/CU.
// 4 ci-phases x 14 tap-pair groups (MFMA K=32 = 2 taps x 16ch). Steady-loop VMEM queue =
// ONLY A-stages (4 x 32B-coalesced gld16 per group). B in LDS (staged once/phase/block).
// idx: block's nbr slab loaded COALESCED via global_load_lds into scratch (864 x 64B
// requests vs 3.5M strided), redistributed once to 27 VGPRs/lane via ds_read.
template <int EPI>
__global__ __launch_bounds__(512, 1) void conv_bl(
    const unsigned short* __restrict__ xc,    // [NP][NV][CE]
    const unsigned short* __restrict__ wq,    // [NP][NG2][4][64][8]
    const float* __restrict__ bias,           // [64]
    const int* __restrict__ nbr,              // [N][27]
    const float* __restrict__ resid,          // [N][64] f32 (EPI==1)
    unsigned short* __restrict__ hc,          // EPI0 out: [NP][NV][CE]
    float* __restrict__ outf)                 // EPI1 out: [N][64] f32
{
    __shared__ char lds[155648];              // ringA 96KB | ldsB 56KB (also idx scratch)
    char* const ringA = lds;                  // [wave][3 pair-slots][4096]
    char* const ldsB  = lds + 98304;          // [group][nt][lane][16B] (56 KB)
    const int tid  = threadIdx.x;
    const int wid  = tid >> 6;
    const int lane = tid & 63;
    const int lr   = lane & 15;
    const int kg   = lane >> 4;
    const int rowb = blockIdx.x * 512 + wid * 64;

    // --- coalesced idx load: nbr slab (512*27*4 = 55296 B) -> ldsB scratch -> VGPRs ---
    int idx[KK];
    {
        const char* src = (const char*)(nbr + (size_t)blockIdx.x * 512 * KK);
        #pragma unroll
        for (int i = 0; i < 7; ++i) {
            int off = i * 8192 + tid * 16;
            if (off < 55296) gld16(src + off, ldsB + off);
        }
        asm volatile("s_waitcnt vmcnt(0)" ::: "memory");
        __syncthreads();
        const char* my = ldsB + (size_t)(wid * 64 + lane) * (KK * 4);
        #pragma unroll
        for (int k = 0; k < KK; ++k)
            idx[k] = *reinterpret_cast<const int*>(my + k * 4);
        asm volatile("s_waitcnt lgkmcnt(0)" ::: "memory");
        __syncthreads();                      // reads done before phase-0 B staging lands
    }

    f32x4 acc[4][4];
    #pragma unroll
    for (int rt = 0; rt < 4; ++rt)
        #pragma unroll
        for (int nt = 0; nt < 4; ++nt)
            acc[rt][nt] = (f32x4){0.f, 0.f, 0.f, 0.f};

    char* const myring = ringA + wid * 12288;

    // stage pair-group g (taps 2g, 2g+1): 4 gld16, paired lanes -> 32B coalesced requests.
    // slot layout [tap][row][32B]; lane l covers row l>>1 (+32), half (l&1).
    auto stageg = [&](int g, const unsigned short* xcc) {
        char* dst = myring + (g % 3) * 4096;
        const int k0 = 2 * g, k1 = (2 * g + 1 < KK) ? 2 * g + 1 : KK - 1;  // pad tap: W==0
        int r = lane >> 1, h = (lane & 1) * 8;
        int v00 = __shfl(idx[k0], r), v01 = __shfl(idx[k0], 32 + r);
        int v10 = __shfl(idx[k1], r), v11 = __shfl(idx[k1], 32 + r);
        gld16(xcc + (size_t)v00 * CE + h, dst);
        gld16(xcc + (size_t)v01 * CE + h, dst + 1024);
        gld16(xcc + (size_t)v10 * CE + h, dst + 2048);
        gld16(xcc + (size_t)v11 * CE + h, dst + 3072);
    };

    #pragma unroll 1
    for (int p = 0; p < NP; ++p) {
        const unsigned short* xcc = xc + (size_t)p * NV * CE;
        const char* wqp = (const char*)wq + (size_t)p * NG2 * 4096;

        if (p) __syncthreads();               // all waves done reading old B
        // B for the whole phase: 7 contiguous gld16 per thread (56 KB / block)
        #pragma unroll
        for (int i = 0; i < 7; ++i) {
            int off = (i * 8 + wid) * 1024;
            gld16(wqp + off + lane * 16, ldsB + off);
        }
        FENCE;
        stageg(0, xcc); FENCE;
        stageg(1, xcc); FENCE;
        stageg(2, xcc); FENCE;
        asm volatile("s_waitcnt vmcnt(8)" ::: "memory");   // B + A(0) done; A(1),A(2) in flight
        __syncthreads();                       // everyone's B slice landed

        #pragma unroll
        for (int g = 0; g < NG2; ++g) {
            if      (g < NG2 - 2) asm volatile("s_waitcnt vmcnt(8)" ::: "memory");
            else if (g == NG2-2)  asm volatile("s_waitcnt vmcnt(4)" ::: "memory");
            else                  asm volatile("s_waitcnt vmcnt(0)" ::: "memory");

            const char* ab = myring + (g % 3) * 4096 + (kg >> 1) * 2048;
            short8 a_[4];
            #pragma unroll
            for (int rt = 0; rt < 4; ++rt)
                a_[rt] = *reinterpret_cast<const short8*>(ab + (rt * 16 + lr) * 32 + (kg & 1) * 16);
            short8 b_[4];
            #pragma unroll
            for (int nt = 0; nt < 4; ++nt)
                b_[nt] = *reinterpret_cast<const short8*>(ldsB + g * 4096 + nt * 1024 + lane * 16);
            asm volatile("s_waitcnt lgkmcnt(0)" ::: "memory");
            __builtin_amdgcn_sched_barrier(0);

            if (g + 3 < NG2) { stageg(g + 3, xcc); }
            FENCE;

            #pragma unroll
            for (int rt = 0; rt < 4; ++rt)
                #pragma unroll
                for (int nt = 0; nt < 4; ++nt)
                    acc[rt][nt] = __builtin_amdgcn_mfma_f32_16x16x32_bf16(
                        a_[rt], b_[nt], acc[rt][nt], 0, 0, 0);
        }
    }

    // Epilogue. D: col = nt*16+lr, row = rowb + rt*16 + kg*4 + i
    #pragma unroll
    for (int rt = 0; rt < 4; ++rt) {
        const int row0 = rowb + rt * 16 + kg * 4;
        #pragma unroll
        for (int nt = 0; nt < 4; ++nt) {
            int col = nt * 16 + lr;
            float bv = bias[col];
            #pragma unroll
            for (int i = 0; i < 4; ++i) {
                float v = acc[rt][nt][i] + bv;
                if (EPI == 0) {
                    v = fmaxf(v, 0.f);
                    hc[((size_t)nt * NV + (row0 + i)) * CE + lr] = f2b(v);
                } else {
                    v += __builtin_nontemporal_load(resid + (size_t)(row0 + i) * CH + col);
                    v = fmaxf(v, 0.f);
                    __builtin_nontemporal_store(v, outf + (size_t)(row0 + i) * CH + col);
                }
            }
        }
    }
}

extern "C" void kernel_launch(void* const* d_in, const int* in_sizes, int n_in,
                              void* d_out, int out_size, void* d_ws, size_t ws_size,
                              hipStream_t stream) {
    const float* feat = (const float*)d_in[0];
    const float* W1   = (const float*)d_in[1];
    const float* b1   = (const float*)d_in[2];
    const float* W2   = (const float*)d_in[3];
    const float* b2   = (const float*)d_in[4];
    const int*   nbr  = (const int*)d_in[5];
    float* out = (float*)d_out;

    const int PER = NP * NG2 * 4 * 64 * 8;                                     // 114688
    char* ws = (char*)d_ws;
    unsigned short* xcb = (unsigned short*)ws;                                 // 16.78 MB
    unsigned short* hcb = (unsigned short*)(ws + (size_t)NV * CH * 2);         // 16.78 MB
    unsigned short* wq1 = (unsigned short*)(ws + (size_t)NV * CH * 4);         // 229 KB
    unsigned short* wq2 = wq1 + PER;                                           // 229 KB

    prep_featc<<<NV * 16 / 256, 256, 0, stream>>>(feat, xcb);
    prep_wq<<<2 * PER / 256, 256, 0, stream>>>(W1, W2, wq1, wq2);
    conv_bl<0><<<NV / 512, 512, 0, stream>>>(xcb, wq1, b1, nbr, nullptr, hcb, nullptr);
    conv_bl<1><<<NV / 512, 512, 0, stream>>>(hcb, wq2, b2, nbr, feat, nullptr, out);
}